// Round 11
// baseline (49.058 us; speedup 1.0000x reference)
//
#include <hip/hip_runtime.h>
#include <hip/hip_bf16.h>

#define HRr 30
#define WRr 40
#define MM 1200      // HRr*WRr
#define CC 128
#define NB 8
#define GS 8

constexpr int PT = 19;                   // 64-col fragment tiles per dim (ws layout)
constexpr int TILE_SH = 16 * 64 * 8;     // shorts per (n,tile) fragment block = 8192
constexpr int NPART = 2400;              // 8 images x 75 strips x 4 col-quarters
constexpr int CV_THREADS = 19 * 8 * 8 * 256;   // convert grid total threads

typedef __attribute__((ext_vector_type(8))) short bf16x8;
typedef __attribute__((ext_vector_type(4))) float f32x4;

__device__ inline short f2bf(float f) {
    union { float f; unsigned u; } v; v.f = f;
    unsigned r = v.u + 0x7FFFu + ((v.u >> 16) & 1u);   // RNE
    return (short)(r >> 16);
}

// ------- Kernel A: fused {reduced mask, f32->bf16 fragment convert, shared s-plane} -------
// ws layout per (n, tile): [ks 0..3][rb 0..3][lane 0..63][8 halfwords]
// Grid (PT, 8, NB): block handles 2 k-runs; wave g: k-run y*2+(g>>1), operand g&1.
// s_plane: s[p][q] is identical for all n (homo shared across batch) -> computed ONCE here.
__global__ __launch_bounds__(256) void convert_prep_kernel(const float* __restrict__ des1,
                                                           const float* __restrict__ des2,
                                                           const float* __restrict__ homo,
                                                           const float* __restrict__ mask,
                                                           short* __restrict__ wsA,
                                                           short* __restrict__ wsB,
                                                           float* __restrict__ s_plane,
                                                           float* __restrict__ out_rmask,
                                                           float* __restrict__ ws_rmask) {
    const int t     = threadIdx.x;
    const int ptile = blockIdx.x;      // 0..18
    const int n     = blockIdx.z;      // 0..7

    // ---- prep part (y==0 blocks; 152*256 = 38912 threads cover 9600) ----
    if (blockIdx.y == 0) {
        const int gid = (blockIdx.z * gridDim.x + blockIdx.x) * 256 + t;
        if (gid < NB * MM) {
            int nn = gid / MM;
            int rem = gid % MM;
            int k = rem / WRr, l = rem % WRr;
            const float* mp = mask + (size_t)nn * (240 * 320) + (size_t)(k * GS) * 320 + l * GS;
            float prod = 1.f;
            #pragma unroll
            for (int yy = 0; yy < GS; ++yy) {
                float4 a = *reinterpret_cast<const float4*>(&mp[yy * 320]);
                float4 b = *reinterpret_cast<const float4*>(&mp[yy * 320 + 4]);
                prod *= a.x * a.y * a.z * a.w * b.x * b.y * b.z * b.w;
            }
            out_rmask[gid] = prod;
            ws_rmask[gid]  = prod;
        }
    }

    // ---- convert part ----
    const int lane = t & 63;           // row within tile
    const int g    = t >> 6;           // wave id
    const int p    = ptile * 64 + lane;
    const int kr   = blockIdx.y * 2 + (g >> 1);   // k-run 0..15
    const int kb   = kr * 8;
    const int isB  = g & 1;

    const float* src = (isB ? des2 : des1) + (size_t)n * CC * MM;
    short* dst = (isB ? wsB : wsA) + (size_t)(n * PT + ptile) * TILE_SH;

    bf16x8 wv;
    #pragma unroll
    for (int i = 0; i < 8; ++i) {
        float v = (p < MM) ? src[(size_t)(kb + i) * MM + p] : 0.f;   // coalesced per i
        wv[i] = f2bf(v);
    }
    const int rb = lane >> 4, lc = lane & 15;
    const int ks = kr >> 2, lrk = kr & 3;
    const size_t off = (size_t)(((ks * 4 + rb) * 64) + lrk * 16 + lc) * 8;
    *reinterpret_cast<bf16x8*>(&dst[off]) = wv;

    // ---- shared s-plane: 1.44M elements over all 311,296 threads (<=5 each) ----
    const float h0 = homo[0], h1 = homo[1], h2 = homo[2];
    const float h3 = homo[3], h4 = homo[4], h5 = homo[5];
    const float h6 = homo[6], h7 = homo[7], h8 = homo[8];
    const int gidS = ((blockIdx.z * gridDim.y + blockIdx.y) * gridDim.x + blockIdx.x) * 256 + t;
    for (int i = gidS; i < MM * MM; i += CV_THREADS) {
        const int pp = i / MM, qq = i - pp * MM;
        const float gx = (float)((pp % WRr) * GS + GS / 2);
        const float gy = (float)((pp / WRr) * GS + GS / 2);
        const float x = (float)((qq % WRr) * GS + GS / 2);
        const float y = (float)((qq / WRr) * GS + GS / 2);
        const float nx = h0 * x + h1 * y + h2;
        const float ny = h3 * x + h4 * y + h5;
        const float dn = h6 * x + h7 * y + h8;
        const float wx = nx / dn, wy = ny / dn;
        const float dx = gx - wx, dy = gy - wy;
        const float dist = sqrtf(dx * dx + dy * dy);
        s_plane[i] = (dist <= 7.5f) ? 1.f : 0.f;
    }
}

// ---------------- Kernel B: quarter-strip MFMA GEMM + line-aligned epilogue ----------------
// Block = (n, 16-row strip, col quarter). 2400 blocks, 19.7 KB LDS -> 8 blocks/CU.
// Epilogue: dot from LDS + s from the shared s_plane (no sqrt, no wgrid) ->
// le = s ? 250*pos : neg (bit-exact for s in {0,1}).
__global__ __launch_bounds__(256) void main_kernel(const short* __restrict__ wsA,
                                                   const short* __restrict__ wsB,
                                                   const float* __restrict__ s_plane,
                                                   const float* __restrict__ rmask,
                                                   float* __restrict__ out_s,
                                                   float* __restrict__ out_dot,
                                                   float* __restrict__ partials) {
    __shared__ float Ds[16 * 308];    // 16 rows x <=304 cols (+1 shift), stride 308
    __shared__ float red[4];

    const int f   = blockIdx.x;                      // 0..2399
    const int lid = (f & 7) * 300 + (f >> 3);        // image (f&7) -> XCD (f%8)
    const int n       = lid / 300;
    const int rem     = lid % 300;
    const int strip   = rem >> 2;
    const int quarter = rem & 3;
    const int p0    = strip * 16;
    const int cbase = quarter * 304;
    const int nf    = (quarter < 3) ? 19 : 18;    // col-frags this quarter
    const int W     = (quarter < 3) ? 304 : 288;  // cols this quarter
    const int fbase = quarter * 19;

    const int t    = threadIdx.x;
    const int lane = t & 63;
    const int w    = t >> 6;
    const int lr   = lane >> 4, lc = lane & 15;

    // A fragments for rows p0..p0+15, all 4 k-slices
    const short* An  = wsA + (size_t)(n * PT + (p0 >> 6)) * TILE_SH;
    const int    rbA = (p0 >> 4) & 3;
    bf16x8 af[4];
    #pragma unroll
    for (int ks = 0; ks < 4; ++ks)
        af[ks] = *reinterpret_cast<const bf16x8*>(&An[(size_t)(((ks * 4 + rbA) * 64) + lane) * 8]);

    const short* Bn = wsB + (size_t)n * PT * TILE_SH;
    const float* rm = rmask + n * MM;

    // ---- compute: each wave takes col-frags i = w, w+4, ... ----
    for (int i = w; i < nf; i += 4) {
        const int g = fbase + i;                       // global col-frag 0..74
        const short* Bt = Bn + (size_t)(g >> 2) * TILE_SH;
        const int rbB = g & 3;
        f32x4 acc = {0.f, 0.f, 0.f, 0.f};
        #pragma unroll
        for (int ks = 0; ks < 4; ++ks) {
            bf16x8 bfr = *reinterpret_cast<const bf16x8*>(
                &Bt[(size_t)(((ks * 4 + rbB) * 64) + lane) * 8]);
            acc = __builtin_amdgcn_mfma_f32_16x16x32_bf16(af[ks], bfr, acc, 0, 0, 0);
        }
        #pragma unroll
        for (int r = 0; r < 4; ++r)
            Ds[(lr * 4 + r) * 308 + 1 + i * 16 + lc] = acc[r];   // D row=lr*4+r, col=lc
    }
    __syncthreads();

    // ---- write phase: each 16-lane group owns one row ----
    const int row = t >> 4;
    const int l16 = t & 15;
    const int p   = p0 + row;
    const size_t rowbase = (size_t)(n * MM + p) * MM;
    const float* sp = s_plane + (size_t)p * MM;      // shared s row (same for all n)
    const int h = 31 - 16 * (p & 1);                 // global aligned-col phase
    const int cAl = (((h - cbase) % 32) + 32) % 32;  // first aligned local col

    float lsum = 0.f;

    for (int c = l16; c < cAl; c += 16) {
        const float dot = Ds[row * 308 + 1 + c];
        const int q = cbase + c;
        const float s = sp[q];
        const float pos = fmaxf(1.f - dot, 0.f);
        const float neg = fmaxf(dot - 0.2f, 0.f);
        const float le = (s != 0.f) ? 250.f * pos : neg;
        lsum += le * rm[q];
        out_dot[rowbase + q] = dot;
        out_s[rowbase + q] = s;
    }
    const int nl = (W - cAl) >> 5;      // full 128B lines in body
    const int s4 = nl << 3;             // float4 slots
    const int ts = cAl + (nl << 5);     // tail start (rel col)
    for (int k = 0;; ++k) {
        const int jj = l16 + (k << 4);
        if (jj >= s4) break;
        const int c = cAl + (jj << 2);
        const int q = cbase + c;
        const f32x4 dv = *reinterpret_cast<const f32x4*>(&Ds[row * 308 + 1 + c]);
        const f32x4 sv = *reinterpret_cast<const f32x4*>(&sp[q]);   // aligned (+1-shifted plane)
        #pragma unroll
        for (int u = 0; u < 4; ++u) {
            const float pos = fmaxf(1.f - dv[u], 0.f);
            const float neg = fmaxf(dv[u] - 0.2f, 0.f);
            const float le = (sv[u] != 0.f) ? 250.f * pos : neg;
            lsum += le * rm[q + u];
        }
        *reinterpret_cast<f32x4*>(&out_dot[rowbase + q]) = dv;
        *reinterpret_cast<f32x4*>(&out_s[rowbase + q]) = sv;
    }
    for (int c = ts + l16; c < W; c += 16) {
        const float dot = Ds[row * 308 + 1 + c];
        const int q = cbase + c;
        const float s = sp[q];
        const float pos = fmaxf(1.f - dot, 0.f);
        const float neg = fmaxf(dot - 0.2f, 0.f);
        const float le = (s != 0.f) ? 250.f * pos : neg;
        lsum += le * rm[q];
        out_dot[rowbase + q] = dot;
        out_s[rowbase + q] = s;
    }

    // ---- wave shuffle reduce, then 4-entry combine ----
    #pragma unroll
    for (int off = 32; off > 0; off >>= 1)
        lsum += __shfl_xor(lsum, off, 64);
    if (lane == 0) red[w] = lsum;
    __syncthreads();
    if (t == 0)
        partials[lid] = (red[0] + red[1]) + (red[2] + red[3]);
}

// ---------------- Kernel C: deterministic final reduction (shuffle-based) ----------------
__global__ __launch_bounds__(1024) void final_kernel(const float* __restrict__ partials,
                                                     const float* __restrict__ rmask,
                                                     float* __restrict__ out_loss) {
    __shared__ float r1[16], r2[16];
    const int t = threadIdx.x;
    const int lane = t & 63;
    const int w = t >> 6;

    float s1 = 0.f, s2 = 0.f;
    for (int i = t; i < NPART; i += 1024) s1 += partials[i];
    for (int i = t; i < NB * MM; i += 1024) s2 += rmask[i];
    #pragma unroll
    for (int off = 32; off > 0; off >>= 1) {
        s1 += __shfl_xor(s1, off, 64);
        s2 += __shfl_xor(s2, off, 64);
    }
    if (lane == 0) { r1[w] = s1; r2[w] = s2; }
    __syncthreads();
    if (t == 0) {
        float total = 0.f, rsum = 0.f;
        #pragma unroll
        for (int i = 0; i < 16; ++i) { total += r1[i]; rsum += r2[i]; }
        out_loss[0] = total / ((float)MM * rsum);
    }
}

extern "C" void kernel_launch(void* const* d_in, const int* in_sizes, int n_in,
                              void* d_out, int out_size, void* d_ws, size_t ws_size,
                              hipStream_t stream) {
    const float* des1 = (const float*)d_in[0];
    const float* des2 = (const float*)d_in[1];
    const float* homo = (const float*)d_in[2];
    const float* mask = (const float*)d_in[3];

    float* out      = (float*)d_out;
    float* out_loss = out;                                // 1
    float* out_s    = out + 1;                            // 11,520,000
    float* out_dot  = out + 1 + (size_t)NB * MM * MM;     // 11,520,000
    float* out_rm   = out + 1 + 2 * (size_t)NB * MM * MM; // 9,600

    // workspace layout (byte offsets, all 16B-aligned)
    char* wsb = (char*)d_ws;
    float*  partials = (float*)(wsb + 16384);             //   9,600 B
    float*  ws_rm    = (float*)(wsb + 32768);             //  38,400 B
    // s_plane gets a +1 element shift so &sp[p*MM + q] is 16B-aligned exactly at
    // the output buffers' aligned column phase (q == 31-16*(p&1) mod 32).
    float*  s_plane  = (float*)(wsb + 81920) + 1;         // 5,760,004 B
    short*  wsA      = (short*)(wsb + 5898240);           // 2,490,368 B
    short*  wsB      = wsA + (size_t)NB * PT * TILE_SH;   // 2,490,368 B

    dim3 cgrid(PT, 8, NB);
    convert_prep_kernel<<<cgrid, 256, 0, stream>>>(des1, des2, homo, mask,
                                                   wsA, wsB, s_plane, out_rm, ws_rm);

    main_kernel<<<dim3(NPART, 1, 1), 256, 0, stream>>>(wsA, wsB, s_plane, ws_rm,
                                                       out_s, out_dot, partials);

    final_kernel<<<1, 1024, 0, stream>>>(partials, ws_rm, out_loss);
}

// Round 12
// 38.743 us; speedup vs baseline: 1.2662x; 1.2662x over previous
//
#include <hip/hip_runtime.h>
#include <hip/hip_bf16.h>

#define HRr 30
#define WRr 40
#define MM 1200      // HRr*WRr
#define CC 128
#define NB 8
#define GS 8

constexpr int PT = 19;                   // 64-col fragment tiles per dim (ws layout)
constexpr int TILE_SH = 16 * 64 * 8;     // shorts per (n,tile) fragment block = 8192
constexpr int NPART = 2400;              // 8 images x 75 strips x 4 col-quarters

typedef __attribute__((ext_vector_type(8))) short bf16x8;
typedef __attribute__((ext_vector_type(4))) float f32x4;

__device__ inline short f2bf(float f) {
    union { float f; unsigned u; } v; v.f = f;
    unsigned r = v.u + 0x7FFFu + ((v.u >> 16) & 1u);   // RNE
    return (short)(r >> 16);
}

// ------- Kernel A: fused {warped grid, reduced mask, f32->bf16 fragment convert} -------
// ws layout per (n, tile): [ks 0..3][rb 0..3][lane 0..63][8 halfwords]
// Grid (PT, 8, NB): block handles 2 k-runs; wave g: k-run y*2+(g>>1), operand g&1.
__global__ __launch_bounds__(256) void convert_prep_kernel(const float* __restrict__ des1,
                                                           const float* __restrict__ des2,
                                                           const float* __restrict__ homo,
                                                           const float* __restrict__ mask,
                                                           short* __restrict__ wsA,
                                                           short* __restrict__ wsB,
                                                           float2* __restrict__ wgrid,
                                                           float* __restrict__ out_rmask,
                                                           float* __restrict__ ws_rmask) {
    const int t     = threadIdx.x;
    const int ptile = blockIdx.x;      // 0..18
    const int n     = blockIdx.z;      // 0..7

    // ---- prep part (y==0 blocks; 152*256 = 38912 threads cover 9600) ----
    if (blockIdx.y == 0) {
        const int gid = (blockIdx.z * gridDim.x + blockIdx.x) * 256 + t;
        if (gid < MM) {
            int k = gid / WRr, l = gid % WRr;
            float x = (float)(l * GS + GS / 2);
            float y = (float)(k * GS + GS / 2);
            float nx = homo[0] * x + homo[1] * y + homo[2];
            float ny = homo[3] * x + homo[4] * y + homo[5];
            float dn = homo[6] * x + homo[7] * y + homo[8];
            wgrid[gid] = make_float2(nx / dn, ny / dn);
        }
        if (gid < NB * MM) {
            int nn = gid / MM;
            int rem = gid % MM;
            int k = rem / WRr, l = rem % WRr;
            const float* mp = mask + (size_t)nn * (240 * 320) + (size_t)(k * GS) * 320 + l * GS;
            float prod = 1.f;
            #pragma unroll
            for (int yy = 0; yy < GS; ++yy) {
                float4 a = *reinterpret_cast<const float4*>(&mp[yy * 320]);
                float4 b = *reinterpret_cast<const float4*>(&mp[yy * 320 + 4]);
                prod *= a.x * a.y * a.z * a.w * b.x * b.y * b.z * b.w;
            }
            out_rmask[gid] = prod;
            ws_rmask[gid]  = prod;
        }
    }

    // ---- convert part ----
    const int lane = t & 63;           // row within tile
    const int g    = t >> 6;           // wave id
    const int p    = ptile * 64 + lane;
    const int kr   = blockIdx.y * 2 + (g >> 1);   // k-run 0..15
    const int kb   = kr * 8;
    const int isB  = g & 1;

    const float* src = (isB ? des2 : des1) + (size_t)n * CC * MM;
    short* dst = (isB ? wsB : wsA) + (size_t)(n * PT + ptile) * TILE_SH;

    bf16x8 wv;
    #pragma unroll
    for (int i = 0; i < 8; ++i) {
        float v = (p < MM) ? src[(size_t)(kb + i) * MM + p] : 0.f;   // coalesced per i
        wv[i] = f2bf(v);
    }
    const int rb = lane >> 4, lc = lane & 15;
    const int ks = kr >> 2, lrk = kr & 3;
    const size_t off = (size_t)(((ks * 4 + rb) * 64) + lrk * 16 + lc) * 8;
    *reinterpret_cast<bf16x8*>(&dst[off]) = wv;
}

// ---------------- Kernel B: quarter-strip MFMA GEMM + line-aligned epilogue ----------------
// Block = (n, 16-row strip, col quarter). 2400 blocks, 19.7 KB LDS -> 8 blocks/CU.
// s via squared-distance compare (7.5^2 = 56.25, both exact; no sqrt).
__global__ __launch_bounds__(256) void main_kernel(const short* __restrict__ wsA,
                                                   const short* __restrict__ wsB,
                                                   const float2* __restrict__ wgrid,
                                                   const float* __restrict__ rmask,
                                                   float* __restrict__ out_s,
                                                   float* __restrict__ out_dot,
                                                   float* __restrict__ partials) {
    __shared__ float Ds[16 * 308];    // 16 rows x <=304 cols (+1 shift), stride 308
    __shared__ float red[4];

    const int f   = blockIdx.x;                      // 0..2399
    const int lid = (f & 7) * 300 + (f >> 3);        // image (f&7) -> XCD (f%8)
    const int n       = lid / 300;
    const int rem     = lid % 300;
    const int strip   = rem >> 2;
    const int quarter = rem & 3;
    const int p0    = strip * 16;
    const int cbase = quarter * 304;
    const int nf    = (quarter < 3) ? 19 : 18;    // col-frags this quarter
    const int W     = (quarter < 3) ? 304 : 288;  // cols this quarter
    const int fbase = quarter * 19;

    const int t    = threadIdx.x;
    const int lane = t & 63;
    const int w    = t >> 6;
    const int lr   = lane >> 4, lc = lane & 15;

    // A fragments for rows p0..p0+15, all 4 k-slices
    const short* An  = wsA + (size_t)(n * PT + (p0 >> 6)) * TILE_SH;
    const int    rbA = (p0 >> 4) & 3;
    bf16x8 af[4];
    #pragma unroll
    for (int ks = 0; ks < 4; ++ks)
        af[ks] = *reinterpret_cast<const bf16x8*>(&An[(size_t)(((ks * 4 + rbA) * 64) + lane) * 8]);

    const short* Bn = wsB + (size_t)n * PT * TILE_SH;
    const float* rm = rmask + n * MM;

    // ---- compute: each wave takes col-frags i = w, w+4, ... ----
    for (int i = w; i < nf; i += 4) {
        const int g = fbase + i;                       // global col-frag 0..74
        const short* Bt = Bn + (size_t)(g >> 2) * TILE_SH;
        const int rbB = g & 3;
        f32x4 acc = {0.f, 0.f, 0.f, 0.f};
        #pragma unroll
        for (int ks = 0; ks < 4; ++ks) {
            bf16x8 bfr = *reinterpret_cast<const bf16x8*>(
                &Bt[(size_t)(((ks * 4 + rbB) * 64) + lane) * 8]);
            acc = __builtin_amdgcn_mfma_f32_16x16x32_bf16(af[ks], bfr, acc, 0, 0, 0);
        }
        #pragma unroll
        for (int r = 0; r < 4; ++r)
            Ds[(lr * 4 + r) * 308 + 1 + i * 16 + lc] = acc[r];   // D row=lr*4+r, col=lc
    }
    __syncthreads();

    // ---- write phase: each 16-lane group owns one row ----
    const int row = t >> 4;
    const int l16 = t & 15;
    const int p   = p0 + row;
    const float gx = (float)((p % WRr) * GS + GS / 2);
    const float gy = (float)((p / WRr) * GS + GS / 2);
    const size_t rowbase = (size_t)(n * MM + p) * MM;
    const float* dsr = &Ds[row * 308 + 1];
    const int h = 31 - 16 * (p & 1);             // global aligned-col phase
    const int cAl = (((h - cbase) % 32) + 32) % 32;   // first aligned local col

    float a0 = 0.f, a1 = 0.f, a2 = 0.f, a3 = 0.f;   // split accumulators

    for (int c = l16; c < cAl; c += 16) {
        const float dot = dsr[c];
        const int q = cbase + c;
        const float2 wg = wgrid[q];
        const float dx = gx - wg.x, dy = gy - wg.y;
        const float d2 = dx * dx + dy * dy;
        const float s = (d2 <= 56.25f) ? 1.f : 0.f;
        const float le = 250.f * s * fmaxf(1.f - dot, 0.f) + (1.f - s) * fmaxf(dot - 0.2f, 0.f);
        a0 += le * rm[q];
        out_dot[rowbase + q] = dot;
        out_s[rowbase + q] = s;
    }
    const int nl = (W - cAl) >> 5;      // full 128B lines in body
    const int s4 = nl << 3;             // float4 slots
    const int ts = cAl + (nl << 5);     // tail start (rel col)
    for (int k = 0;; ++k) {
        const int jj = l16 + (k << 4);
        if (jj >= s4) break;
        const int c = cAl + (jj << 2);
        const int q = cbase + c;
        const f32x4 dv = *reinterpret_cast<const f32x4*>(&dsr[c]);
        f32x4 sv;
        {
            const float2 wg0 = wgrid[q];
            const float2 wg1 = wgrid[q + 1];
            const float2 wg2 = wgrid[q + 2];
            const float2 wg3 = wgrid[q + 3];
            const float dx0 = gx - wg0.x, dy0 = gy - wg0.y;
            const float dx1 = gx - wg1.x, dy1 = gy - wg1.y;
            const float dx2 = gx - wg2.x, dy2 = gy - wg2.y;
            const float dx3 = gx - wg3.x, dy3 = gy - wg3.y;
            sv[0] = (dx0 * dx0 + dy0 * dy0 <= 56.25f) ? 1.f : 0.f;
            sv[1] = (dx1 * dx1 + dy1 * dy1 <= 56.25f) ? 1.f : 0.f;
            sv[2] = (dx2 * dx2 + dy2 * dy2 <= 56.25f) ? 1.f : 0.f;
            sv[3] = (dx3 * dx3 + dy3 * dy3 <= 56.25f) ? 1.f : 0.f;
        }
        const float le0 = 250.f * sv[0] * fmaxf(1.f - dv[0], 0.f) + (1.f - sv[0]) * fmaxf(dv[0] - 0.2f, 0.f);
        const float le1 = 250.f * sv[1] * fmaxf(1.f - dv[1], 0.f) + (1.f - sv[1]) * fmaxf(dv[1] - 0.2f, 0.f);
        const float le2 = 250.f * sv[2] * fmaxf(1.f - dv[2], 0.f) + (1.f - sv[2]) * fmaxf(dv[2] - 0.2f, 0.f);
        const float le3 = 250.f * sv[3] * fmaxf(1.f - dv[3], 0.f) + (1.f - sv[3]) * fmaxf(dv[3] - 0.2f, 0.f);
        a0 += le0 * rm[q];
        a1 += le1 * rm[q + 1];
        a2 += le2 * rm[q + 2];
        a3 += le3 * rm[q + 3];
        *reinterpret_cast<f32x4*>(&out_dot[rowbase + q]) = dv;
        *reinterpret_cast<f32x4*>(&out_s[rowbase + q]) = sv;
    }
    for (int c = ts + l16; c < W; c += 16) {
        const float dot = dsr[c];
        const int q = cbase + c;
        const float2 wg = wgrid[q];
        const float dx = gx - wg.x, dy = gy - wg.y;
        const float d2 = dx * dx + dy * dy;
        const float s = (d2 <= 56.25f) ? 1.f : 0.f;
        const float le = 250.f * s * fmaxf(1.f - dot, 0.f) + (1.f - s) * fmaxf(dot - 0.2f, 0.f);
        a1 += le * rm[q];
        out_dot[rowbase + q] = dot;
        out_s[rowbase + q] = s;
    }

    float lsum = (a0 + a1) + (a2 + a3);

    // ---- wave shuffle reduce, then 4-entry combine ----
    #pragma unroll
    for (int off = 32; off > 0; off >>= 1)
        lsum += __shfl_xor(lsum, off, 64);
    if (lane == 0) red[w] = lsum;
    __syncthreads();
    if (t == 0)
        partials[lid] = (red[0] + red[1]) + (red[2] + red[3]);
}

// ---------------- Kernel C: deterministic final reduction (shuffle-based) ----------------
__global__ __launch_bounds__(1024) void final_kernel(const float* __restrict__ partials,
                                                     const float* __restrict__ rmask,
                                                     float* __restrict__ out_loss) {
    __shared__ float r1[16], r2[16];
    const int t = threadIdx.x;
    const int lane = t & 63;
    const int w = t >> 6;

    float s1 = 0.f, s2 = 0.f;
    for (int i = t; i < NPART; i += 1024) s1 += partials[i];
    for (int i = t; i < NB * MM; i += 1024) s2 += rmask[i];
    #pragma unroll
    for (int off = 32; off > 0; off >>= 1) {
        s1 += __shfl_xor(s1, off, 64);
        s2 += __shfl_xor(s2, off, 64);
    }
    if (lane == 0) { r1[w] = s1; r2[w] = s2; }
    __syncthreads();
    if (t == 0) {
        float total = 0.f, rsum = 0.f;
        #pragma unroll
        for (int i = 0; i < 16; ++i) { total += r1[i]; rsum += r2[i]; }
        out_loss[0] = total / ((float)MM * rsum);
    }
}

extern "C" void kernel_launch(void* const* d_in, const int* in_sizes, int n_in,
                              void* d_out, int out_size, void* d_ws, size_t ws_size,
                              hipStream_t stream) {
    const float* des1 = (const float*)d_in[0];
    const float* des2 = (const float*)d_in[1];
    const float* homo = (const float*)d_in[2];
    const float* mask = (const float*)d_in[3];

    float* out      = (float*)d_out;
    float* out_loss = out;                                // 1
    float* out_s    = out + 1;                            // 11,520,000
    float* out_dot  = out + 1 + (size_t)NB * MM * MM;     // 11,520,000
    float* out_rm   = out + 1 + 2 * (size_t)NB * MM * MM; // 9,600

    // workspace layout (byte offsets, all 16B-aligned)
    char* wsb = (char*)d_ws;
    float2* wgrid    = (float2*)(wsb);                    //   9,600 B
    float*  partials = (float*)(wsb + 16384);             //   9,600 B
    float*  ws_rm    = (float*)(wsb + 32768);             //  38,400 B
    short*  wsA      = (short*)(wsb + 131072);            // 2,490,368 B
    short*  wsB      = wsA + (size_t)NB * PT * TILE_SH;   // 2,490,368 B

    dim3 cgrid(PT, 8, NB);
    convert_prep_kernel<<<cgrid, 256, 0, stream>>>(des1, des2, homo, mask,
                                                   wsA, wsB, wgrid, out_rm, ws_rm);

    main_kernel<<<dim3(NPART, 1, 1), 256, 0, stream>>>(wsA, wsB, wgrid, ws_rm,
                                                       out_s, out_dot, partials);

    final_kernel<<<1, 1024, 0, stream>>>(partials, ws_rm, out_loss);
}